// Round 4
// baseline (138.333 us; speedup 1.0000x reference)
//
#include <hip/hip_runtime.h>
#include <math.h>

// Problem constants (fixed by the reference's setup_inputs)
#define CLS 2
#define BATCH 8
#define HH 512
#define WW 512
#define INV_SCALE 0.125f
#define LOGEPS -16.118095651f   // log(1e-7)
#define NLN2 -0.69314718056f    // -ln(2): folds negate into log2->ln conversion

#define MAXT 192     // LDS capacity for per-batch targets (nT<=160 total)
#define NBLK 2048    // grid: 8*512*512 px / 1024 px-per-block

// ws layout:
//   double gsumd[4][NBLK]  @ 0      (65536 B)  obj_c0, obj_c1, noobj_c0, noobj_c1
//   int    gcnti[2][NBLK]  @ 65536  (16384 B)  packed obj / noobj counts
//   int    ticket          @ 81920  (    4 B)  zeroed by hipMemsetAsync node
// gsumd/gcnti written unconditionally by every block -> no zero-init needed.

// Fused kernel: per-block target staging + per-wave 256-px strip processing
// (4 px/lane) + per-block partial write + LAST-BLOCK-DONE finalize
// (release fence -> ticket atomicAdd -> last block acquires & reduces).
// No grid barrier, no spin: round-2's cg::sync disaster is structurally avoided.
__global__ __launch_bounds__(256) void heatmap_main(
    const float* __restrict__ predict, const float* __restrict__ targets,
    int nT, float* __restrict__ out,
    double* __restrict__ gsumd, int* __restrict__ gcnti, int* __restrict__ ticket)
{
    __shared__ float s_cs[MAXT], s_sn[MAXT], s_x3[MAXT], s_x4[MAXT],
                     s_y3[MAXT], s_y4[MAXT];
    __shared__ int s_cid[MAXT];
    __shared__ int s_nb;
    __shared__ double s_bs[4][4];
    __shared__ int s_bc[4][4];
    __shared__ int s_last;

    const int tid = threadIdx.x;
    const int blockPix = blockIdx.x << 10;      // 1024 px per block
    const int b = blockPix >> 18;               // batch; uniform per block

    // --- stage this batch's targets into LDS (compacted) ---
    if (tid == 0) s_nb = 0;
    __syncthreads();
    for (int t0 = tid; t0 < nT; t0 += 256) {
        const float* tp = targets + t0 * 7;
        if ((int)tp[0] == b) {
            const float cs = cosf(tp[6]), sn = sinf(tp[6]);
            const float cx = tp[2] * INV_SCALE, cy = tp[3] * INV_SCALE;
            const float w_ = tp[4] * INV_SCALE, h_ = tp[5] * INV_SCALE;
            const float x =  cx * cs + cy * sn;
            const float y = -cx * sn + cy * cs;
            const int slot = atomicAdd(&s_nb, 1);
            s_cs[slot] = cs; s_sn[slot] = sn;
            s_x3[slot] = x - 0.5f * h_; s_x4[slot] = x + 0.5f * h_;
            s_y3[slot] = y - 0.5f * w_; s_y4[slot] = y + 0.5f * w_;
            s_cid[slot] = (int)tp[1];
        }
    }
    __syncthreads();
    const int nb = s_nb;

    const int wid = tid >> 6, l = tid & 63;
    const int spix = blockPix + (wid << 8);     // strip base pixel
    const int i  = (spix >> 9) & (HH - 1);      // row
    const int j0 = spix & (WW - 1);             // 0 or 256
    const float gy = (float)i + 0.5f;
    const int j = j0 + 4 * l;                   // 4 px per lane
    const float gxb = (float)j + 0.5f;

    int objm[4] = {0, 0, 0, 0}, outm[4] = {0, 0, 0, 0};

    for (int base = 0; base < nb; base += 64) {
        const int t = base + l;
        bool acc = false;
        if (t < nb) {
            const float cs = s_cs[t], sn = s_sn[t];
            // strip: gx in [j0+0.5, j0+255.5], gy fixed -> exact vx/vy intervals
            const float gxl = (float)j0 + 0.5f, gxh = (float)j0 + 255.5f;
            const float a1 = cs * gxl + sn * gy, a2 = cs * gxh + sn * gy;
            const float b1 = -sn * gxl + cs * gy, b2 = -sn * gxh + cs * gy;
            const float vxlo = fminf(a1, a2), vxhi = fmaxf(a1, a2);
            const float vylo = fminf(b1, b2), vyhi = fmaxf(b1, b2);
            const float M = 0.51f;  // outer margin 0.5 + fp slack
            acc = (vxhi >= s_x3[t] - M) & (vxlo <= s_x4[t] + M) &
                  (vyhi >= s_y3[t] - M) & (vylo <= s_y4[t] + M);
        }
        unsigned long long bal = __ballot(acc);   // wave-uniform hit mask
        while (bal) {
            const int n = base + __builtin_ctzll(bal);  // uniform target index
            bal &= bal - 1;
            // uniform-address LDS reads = hardware broadcast
            const float ccs = s_cs[n], csn = s_sn[n];
            const float cx3 = s_x3[n], cx4 = s_x4[n];
            const float cy3 = s_y3[n], cy4 = s_y4[n];
            const float ox3 = cx3 - 0.5f, ox4 = cx4 + 0.5f;
            const float oy3 = cy3 - 0.5f, oy4 = cy4 + 0.5f;
            const int cbit = 1 << s_cid[n];
            float vx =  ccs * gxb + csn * gy;
            float vy = -csn * gxb + ccs * gy;
            #pragma unroll
            for (int k = 0; k < 4; ++k) {
                const bool in_  = (cx3 <= vx) & (vx <= cx4) &
                                  (cy3 <= vy) & (vy <= cy4);
                const bool out_ = (ox3 <= vx) & (vx <= ox4) &
                                  (oy3 <= vy) & (vy <= oy4);
                if (in_)  objm[k] |= cbit;
                if (out_) outm[k] |= cbit;
                vx += ccs; vy -= csn;
            }
        }
    }

    // --- epilogue: unconditional noobj accumulation, rare correction branch ---
    const int pbase = (b * CLS * HH + i) * WW + j;   // 16B-aligned (j = 4l)
    const float4 P0 = *(const float4*)(predict + pbase);
    const float4 P1 = *(const float4*)(predict + pbase + HH * WW);
    float p0[4], p1[4], l0n[4], l1n[4];
    p0[0]=P0.x; p0[1]=P0.y; p0[2]=P0.z; p0[3]=P0.w;
    p1[0]=P1.x; p1[1]=P1.y; p1[2]=P1.z; p1[3]=P1.w;

    float sq0 = 0.f, sq1 = 0.f;
    float hm[4];
    #pragma unroll
    for (int k = 0; k < 4; ++k) {
        const float t0 = __expf(p0[k]);
        const float t1 = __expf(p1[k]);
        l0n[k] = __log2f(1.0f + t0) * NLN2;   // = log(1-conf0), unclamped
        l1n[k] = __log2f(1.0f + t1) * NLN2;
        sq0 += fmaxf(l0n[k], LOGEPS);
        sq1 += fmaxf(l1n[k], LOGEPS);
        const float tm = fmaxf(t0, t1);
        hm[k] = tm * __builtin_amdgcn_rcpf(1.0f + tm);  // sigmoid(max(p0,p1))
    }
    int cn0 = 4, cn1 = 4, co0 = 0, co1 = 0;
    float so0 = 0.f, so1 = 0.f;
    const int anyout = outm[0] | outm[1] | outm[2] | outm[3];
    if (anyout) {   // rare: only threads whose pixels touch an outer box
        #pragma unroll
        for (int k = 0; k < 4; ++k) {
            if (outm[k] & 1) { sq0 -= fmaxf(l0n[k], LOGEPS); --cn0; }
            if (outm[k] & 2) { sq1 -= fmaxf(l1n[k], LOGEPS); --cn1; }
            if (objm[k] & 1) { so0 += fmaxf(p0[k] + l0n[k], LOGEPS); ++co0; }
            if (objm[k] & 2) { so1 += fmaxf(p1[k] + l1n[k], LOGEPS); ++co1; }
        }
    }

    float* ho = out + 1 + (b * HH + i) * WW + j;  // +1: misaligned -> 4 dwords
    ho[0] = hm[0]; ho[1] = hm[1]; ho[2] = hm[2]; ho[3] = hm[3];

    // --- wave reduction; obj trees skipped wave-uniformly when empty ---
    const unsigned long long anyobj =
        __ballot((objm[0] | objm[1] | objm[2] | objm[3]) != 0);
    int pc = (cn0 & 0xffff) | (cn1 << 16);
    #pragma unroll
    for (int off = 32; off >= 1; off >>= 1) {
        sq0 += __shfl_down(sq0, off);
        sq1 += __shfl_down(sq1, off);
        pc  += __shfl_down(pc, off);
    }
    int po = 0;
    if (anyobj) {
        po = (co0 & 0xffff) | (co1 << 16);
        #pragma unroll
        for (int off = 32; off >= 1; off >>= 1) {
            so0 += __shfl_down(so0, off);
            so1 += __shfl_down(so1, off);
            po  += __shfl_down(po, off);
        }
    }
    if (l == 0) {
        s_bs[wid][0] = (double)so0; s_bs[wid][1] = (double)so1;
        s_bs[wid][2] = (double)sq0; s_bs[wid][3] = (double)sq1;
        s_bc[wid][0] = po;          s_bc[wid][1] = pc;
    }
    __syncthreads();
    // --- per-block partial: plain writes, then release + ticket ---
    if (tid == 0) {
        double o0 = 0, o1 = 0, q0 = 0, q1 = 0;
        int P = 0, Q = 0;  // packed 16-bit fields; <=1024 each, no carry
        #pragma unroll
        for (int w = 0; w < 4; ++w) {
            o0 += s_bs[w][0]; o1 += s_bs[w][1];
            q0 += s_bs[w][2]; q1 += s_bs[w][3];
            P  += s_bc[w][0]; Q  += s_bc[w][1];
        }
        const int blk = blockIdx.x;
        gsumd[0 * NBLK + blk] = o0; gsumd[1 * NBLK + blk] = o1;
        gsumd[2 * NBLK + blk] = q0; gsumd[3 * NBLK + blk] = q1;
        gcnti[0 * NBLK + blk] = P;  gcnti[1 * NBLK + blk] = Q;
        __threadfence();                        // release partials (device scope)
        const int tk = atomicAdd(ticket, 1);    // device-scope (G12 / m20)
        s_last = (tk == NBLK - 1) ? 1 : 0;
    }
    __syncthreads();
    if (!s_last) return;

    // --- last block: acquire + reduce all partials (no spin, no grid sync) ---
    __threadfence();   // acquire: invalidate stale L1/L2 lines (agent scope)
    double f0 = 0, f1 = 0, f2 = 0, f3 = 0;
    int c0 = 0, c1 = 0, c2 = 0, c3 = 0;
    for (int blk = tid; blk < NBLK; blk += 256) {
        // agent-scope atomic loads: coherent across XCDs regardless of
        // whatever the poison-fill left in this XCD's caches
        f0 += __hip_atomic_load(&gsumd[0 * NBLK + blk], __ATOMIC_RELAXED,
                                __HIP_MEMORY_SCOPE_AGENT);
        f1 += __hip_atomic_load(&gsumd[1 * NBLK + blk], __ATOMIC_RELAXED,
                                __HIP_MEMORY_SCOPE_AGENT);
        f2 += __hip_atomic_load(&gsumd[2 * NBLK + blk], __ATOMIC_RELAXED,
                                __HIP_MEMORY_SCOPE_AGENT);
        f3 += __hip_atomic_load(&gsumd[3 * NBLK + blk], __ATOMIC_RELAXED,
                                __HIP_MEMORY_SCOPE_AGENT);
        const int P = __hip_atomic_load(&gcnti[0 * NBLK + blk], __ATOMIC_RELAXED,
                                        __HIP_MEMORY_SCOPE_AGENT);
        const int Q = __hip_atomic_load(&gcnti[1 * NBLK + blk], __ATOMIC_RELAXED,
                                        __HIP_MEMORY_SCOPE_AGENT);
        c0 += P & 0xffff; c1 += (int)((unsigned)P >> 16);   // unpack BEFORE
        c2 += Q & 0xffff; c3 += (int)((unsigned)Q >> 16);   // summing
    }
    #pragma unroll
    for (int off = 32; off >= 1; off >>= 1) {
        f0 += __shfl_down(f0, off); f1 += __shfl_down(f1, off);
        f2 += __shfl_down(f2, off); f3 += __shfl_down(f3, off);
        c0 += __shfl_down(c0, off); c1 += __shfl_down(c1, off);
        c2 += __shfl_down(c2, off); c3 += __shfl_down(c3, off);
    }
    if (l == 0) {
        s_bs[wid][0] = f0; s_bs[wid][1] = f1;
        s_bs[wid][2] = f2; s_bs[wid][3] = f3;
        s_bc[wid][0] = c0; s_bc[wid][1] = c1;
        s_bc[wid][2] = c2; s_bc[wid][3] = c3;
    }
    __syncthreads();
    if (tid == 0) {
        double F[4] = {0, 0, 0, 0}; int C[4] = {0, 0, 0, 0};
        for (int w = 0; w < 4; ++w) {
            F[0] += s_bs[w][0]; F[1] += s_bs[w][1];
            F[2] += s_bs[w][2]; F[3] += s_bs[w][3];
            C[0] += s_bc[w][0]; C[1] += s_bc[w][1];
            C[2] += s_bc[w][2]; C[3] += s_bc[w][3];
        }
        float loss = 0.0f;
        // C[0]=n_obj c0, C[1]=n_obj c1, C[2]=n_noobj c0, C[3]=n_noobj c1
        if (C[0] > 0)
            loss += -(float)F[0] / (float)C[0]
                    - (float)F[2] / (float)(C[2] > 0 ? C[2] : 1);
        if (C[1] > 0)
            loss += -(float)F[1] / (float)C[1]
                    - (float)F[3] / (float)(C[3] > 0 ? C[3] : 1);
        out[0] = loss;  // NO_OBJ_SCALE = 1.0
    }
}

extern "C" void kernel_launch(void* const* d_in, const int* in_sizes, int n_in,
                              void* d_out, int out_size, void* d_ws, size_t ws_size,
                              hipStream_t stream) {
    (void)n_in; (void)out_size; (void)ws_size;
    const float* predict = (const float*)d_in[0];
    const float* targets = (const float*)d_in[1];
    const int nT = in_sizes[1] / 7;
    float* out = (float*)d_out;
    char* ws = (char*)d_ws;
    double* gsumd = (double*)ws;            // 4*2048*8 = 65536 B
    int* gcnti = (int*)(ws + 65536);        // 2*2048*4 = 16384 B
    int* ticket = (int*)(ws + 81920);       // 4 B

    // memset node (capture-legal; harness reset() itself enqueues memsets)
    hipMemsetAsync(ticket, 0, sizeof(int), stream);
    heatmap_main<<<NBLK, 256, 0, stream>>>(predict, targets, nT, out,
                                           gsumd, gcnti, ticket);
}

// Round 5
// 76.914 us; speedup vs baseline: 1.7986x; 1.7986x over previous
//
#include <hip/hip_runtime.h>
#include <math.h>

// Problem constants (fixed by the reference's setup_inputs)
#define CLS 2
#define BATCH 8
#define HH 512
#define WW 512
#define INV_SCALE 0.125f
#define LOGEPS -16.118095651f   // log(1e-7)
#define NLN2 -0.69314718056f    // -ln(2): folds negate into log2->ln conversion

#define MAXT 192     // LDS capacity for per-batch targets (nT<=160 total)
#define NBLK 1024    // grid: 8*512*512 px / 2048 px-per-block

// ws layout (NO zero-init required anywhere — every slot written unconditionally):
//   double gsumd[4][NBLK]  @ 0      (32768 B)  obj_c0, obj_c1, noobj_c0, noobj_c1
//   int    gcnti[2][NBLK]  @ 32768  ( 8192 B)  packed obj / noobj counts
// NOTE (R2/R4 lessons): NO cg grid sync, NO device-fence+ticket tail — both
// cost ~70 us on MI355X (non-coherent XCD L2s make device-scope ordering a
// full L2 writeback/inv). Plain per-block stores + separate tiny finalize
// kernel is the proven-fastest tail (R3 = 77.8 us).

// Fused kernel: per-block coalesced target staging + per-wave 256-px strip
// processing (4 px/lane) + per-block partial write (no global atomics).
// 512 threads = 8 waves; each wave owns one 256-px row strip.
__global__ __launch_bounds__(512) void heatmap_main(
    const float* __restrict__ predict, const float* __restrict__ targets,
    int nT, float* __restrict__ out,
    double* __restrict__ gsumd, int* __restrict__ gcnti)
{
    __shared__ float s_raw[MAXT * 7];           // bulk-staged raw targets
    __shared__ float s_cs[MAXT], s_sn[MAXT], s_x3[MAXT], s_x4[MAXT],
                     s_y3[MAXT], s_y4[MAXT];
    __shared__ int s_cid[MAXT];
    __shared__ int s_nb;
    __shared__ double s_bs[8][4];
    __shared__ int s_bc[8][2];

    const int tid = threadIdx.x;
    const int blockPix = blockIdx.x << 11;      // 2048 px per block
    const int b = blockPix >> 18;               // batch; uniform per block

    // --- coalesced bulk copy of raw targets, then in-LDS transform ---
    if (tid == 0) s_nb = 0;
    for (int q = tid; q < nT * 7; q += 512) s_raw[q] = targets[q];
    __syncthreads();
    if (tid < nT) {
        const float* tp = s_raw + tid * 7;      // stride 7: bank-conflict-free
        if ((int)tp[0] == b) {
            const float cs = cosf(tp[6]), sn = sinf(tp[6]);
            const float cx = tp[2] * INV_SCALE, cy = tp[3] * INV_SCALE;
            const float w_ = tp[4] * INV_SCALE, h_ = tp[5] * INV_SCALE;
            const float x =  cx * cs + cy * sn;
            const float y = -cx * sn + cy * cs;
            const int slot = atomicAdd(&s_nb, 1);
            s_cs[slot] = cs; s_sn[slot] = sn;
            s_x3[slot] = x - 0.5f * h_; s_x4[slot] = x + 0.5f * h_;
            s_y3[slot] = y - 0.5f * w_; s_y4[slot] = y + 0.5f * w_;
            s_cid[slot] = (int)tp[1];
        }
    }
    __syncthreads();
    const int nb = s_nb;

    const int wid = tid >> 6, l = tid & 63;
    const int spix = blockPix + (wid << 8);     // strip base pixel
    const int i  = (spix >> 9) & (HH - 1);      // row
    const int j0 = spix & (WW - 1);             // 0 or 256
    const float gy = (float)i + 0.5f;
    const int j = j0 + 4 * l;                   // 4 px per lane
    const float gxb = (float)j + 0.5f;

    int objm[4] = {0, 0, 0, 0}, outm[4] = {0, 0, 0, 0};

    for (int base = 0; base < nb; base += 64) {
        const int t = base + l;
        bool acc = false;
        if (t < nb) {
            const float cs = s_cs[t], sn = s_sn[t];
            // strip: gx in [j0+0.5, j0+255.5], gy fixed -> exact vx/vy intervals
            const float gxl = (float)j0 + 0.5f, gxh = (float)j0 + 255.5f;
            const float a1 = cs * gxl + sn * gy, a2 = cs * gxh + sn * gy;
            const float b1 = -sn * gxl + cs * gy, b2 = -sn * gxh + cs * gy;
            const float vxlo = fminf(a1, a2), vxhi = fmaxf(a1, a2);
            const float vylo = fminf(b1, b2), vyhi = fmaxf(b1, b2);
            const float M = 0.51f;  // outer margin 0.5 + fp slack
            acc = (vxhi >= s_x3[t] - M) & (vxlo <= s_x4[t] + M) &
                  (vyhi >= s_y3[t] - M) & (vylo <= s_y4[t] + M);
        }
        unsigned long long bal = __ballot(acc);   // wave-uniform hit mask
        while (bal) {
            const int n = base + __builtin_ctzll(bal);  // uniform target index
            bal &= bal - 1;
            // uniform-address LDS reads = hardware broadcast
            const float ccs = s_cs[n], csn = s_sn[n];
            const float cx3 = s_x3[n], cx4 = s_x4[n];
            const float cy3 = s_y3[n], cy4 = s_y4[n];
            const float ox3 = cx3 - 0.5f, ox4 = cx4 + 0.5f;
            const float oy3 = cy3 - 0.5f, oy4 = cy4 + 0.5f;
            const int cbit = 1 << s_cid[n];
            float vx =  ccs * gxb + csn * gy;
            float vy = -csn * gxb + ccs * gy;
            #pragma unroll
            for (int k = 0; k < 4; ++k) {
                const bool in_  = (cx3 <= vx) & (vx <= cx4) &
                                  (cy3 <= vy) & (vy <= cy4);
                const bool out_ = (ox3 <= vx) & (vx <= ox4) &
                                  (oy3 <= vy) & (vy <= oy4);
                if (in_)  objm[k] |= cbit;
                if (out_) outm[k] |= cbit;
                vx += ccs; vy -= csn;
            }
        }
    }

    // --- epilogue: unconditional noobj accumulation, rare correction branch ---
    const int pbase = (b * CLS * HH + i) * WW + j;   // 16B-aligned (j = 4l)
    const float4 P0 = *(const float4*)(predict + pbase);
    const float4 P1 = *(const float4*)(predict + pbase + HH * WW);
    float p0[4], p1[4], l0n[4], l1n[4];
    p0[0]=P0.x; p0[1]=P0.y; p0[2]=P0.z; p0[3]=P0.w;
    p1[0]=P1.x; p1[1]=P1.y; p1[2]=P1.z; p1[3]=P1.w;

    float sq0 = 0.f, sq1 = 0.f;
    float hm[4];
    #pragma unroll
    for (int k = 0; k < 4; ++k) {
        const float t0 = __expf(p0[k]);
        const float t1 = __expf(p1[k]);
        l0n[k] = __log2f(1.0f + t0) * NLN2;   // = log(1-conf0), unclamped
        l1n[k] = __log2f(1.0f + t1) * NLN2;
        sq0 += fmaxf(l0n[k], LOGEPS);
        sq1 += fmaxf(l1n[k], LOGEPS);
        const float tm = fmaxf(t0, t1);
        hm[k] = tm * __builtin_amdgcn_rcpf(1.0f + tm);  // sigmoid(max(p0,p1))
    }
    int cn0 = 4, cn1 = 4, co0 = 0, co1 = 0;
    float so0 = 0.f, so1 = 0.f;
    const int anyout = outm[0] | outm[1] | outm[2] | outm[3];
    if (anyout) {   // rare: only threads whose pixels touch an outer box
        #pragma unroll
        for (int k = 0; k < 4; ++k) {
            if (outm[k] & 1) { sq0 -= fmaxf(l0n[k], LOGEPS); --cn0; }
            if (outm[k] & 2) { sq1 -= fmaxf(l1n[k], LOGEPS); --cn1; }
            if (objm[k] & 1) { so0 += fmaxf(p0[k] + l0n[k], LOGEPS); ++co0; }
            if (objm[k] & 2) { so1 += fmaxf(p1[k] + l1n[k], LOGEPS); ++co1; }
        }
    }

    float* ho = out + 1 + (b * HH + i) * WW + j;  // +1: misaligned -> 4 dwords
    ho[0] = hm[0]; ho[1] = hm[1]; ho[2] = hm[2]; ho[3] = hm[3];

    // --- wave reduction; obj trees skipped wave-uniformly when empty ---
    const unsigned long long anyobj =
        __ballot((objm[0] | objm[1] | objm[2] | objm[3]) != 0);
    int pc = (cn0 & 0xffff) | (cn1 << 16);
    #pragma unroll
    for (int off = 32; off >= 1; off >>= 1) {
        sq0 += __shfl_down(sq0, off);
        sq1 += __shfl_down(sq1, off);
        pc  += __shfl_down(pc, off);
    }
    int po = 0;
    if (anyobj) {
        po = (co0 & 0xffff) | (co1 << 16);
        #pragma unroll
        for (int off = 32; off >= 1; off >>= 1) {
            so0 += __shfl_down(so0, off);
            so1 += __shfl_down(so1, off);
            po  += __shfl_down(po, off);
        }
    }
    if (l == 0) {
        s_bs[wid][0] = (double)so0; s_bs[wid][1] = (double)so1;
        s_bs[wid][2] = (double)sq0; s_bs[wid][3] = (double)sq1;
        s_bc[wid][0] = po;          s_bc[wid][1] = pc;
    }
    __syncthreads();
    // --- per-block partial: plain writes, no atomics, no pre-zeroed ws ---
    if (tid == 0) {
        double o0 = 0, o1 = 0, q0 = 0, q1 = 0;
        int P = 0, Q = 0;  // packed 16-bit fields; <=2048 each, no carry
        #pragma unroll
        for (int w = 0; w < 8; ++w) {
            o0 += s_bs[w][0]; o1 += s_bs[w][1];
            q0 += s_bs[w][2]; q1 += s_bs[w][3];
            P  += s_bc[w][0]; Q  += s_bc[w][1];
        }
        const int blk = blockIdx.x;
        gsumd[0 * NBLK + blk] = o0; gsumd[1 * NBLK + blk] = o1;
        gsumd[2 * NBLK + blk] = q0; gsumd[3 * NBLK + blk] = q1;
        gcnti[0 * NBLK + blk] = P;  gcnti[1 * NBLK + blk] = Q;
    }
}

__global__ __launch_bounds__(512) void heatmap_finalize(
    const double* __restrict__ gsumd, const int* __restrict__ gcnti,
    float* __restrict__ out)
{
    const int t = threadIdx.x;
    double f[4] = {0, 0, 0, 0};
    int co0 = 0, co1 = 0, cn0 = 0, cn1 = 0;
    for (int blk = t; blk < NBLK; blk += 512) {     // coalesced SoA reads
        #pragma unroll
        for (int q = 0; q < 4; ++q) f[q] += gsumd[q * NBLK + blk];
        const int p = gcnti[0 * NBLK + blk];
        const int q2 = gcnti[1 * NBLK + blk];
        co0 += p & 0xffff;  co1 += (int)((unsigned)p >> 16);  // unpack BEFORE
        cn0 += q2 & 0xffff; cn1 += (int)((unsigned)q2 >> 16); // summing
    }
    #pragma unroll
    for (int off = 32; off >= 1; off >>= 1) {
        #pragma unroll
        for (int q = 0; q < 4; ++q) f[q] += __shfl_down(f[q], off);
        co0 += __shfl_down(co0, off); co1 += __shfl_down(co1, off);
        cn0 += __shfl_down(cn0, off); cn1 += __shfl_down(cn1, off);
    }

    __shared__ double sf[8][4];
    __shared__ int    sc[8][4];
    const int wv = t >> 6, ln = t & 63;
    if (ln == 0) {
        #pragma unroll
        for (int q = 0; q < 4; ++q) sf[wv][q] = f[q];
        sc[wv][0] = co0; sc[wv][1] = co1; sc[wv][2] = cn0; sc[wv][3] = cn1;
    }
    __syncthreads();
    if (t == 0) {
        double F[4] = {0, 0, 0, 0}; int C[4] = {0, 0, 0, 0};
        for (int w = 0; w < 8; ++w)
            #pragma unroll
            for (int q = 0; q < 4; ++q) { F[q] += sf[w][q]; C[q] += sc[w][q]; }
        float loss = 0.0f;
        // C[0]=n_obj cls0, C[1]=n_obj cls1, C[2]=n_noobj cls0, C[3]=n_noobj cls1
        if (C[0] > 0)
            loss += -(float)F[0] / (float)C[0]
                    - (float)F[2] / (float)(C[2] > 0 ? C[2] : 1);
        if (C[1] > 0)
            loss += -(float)F[1] / (float)C[1]
                    - (float)F[3] / (float)(C[3] > 0 ? C[3] : 1);
        out[0] = loss;  // NO_OBJ_SCALE = 1.0
    }
}

extern "C" void kernel_launch(void* const* d_in, const int* in_sizes, int n_in,
                              void* d_out, int out_size, void* d_ws, size_t ws_size,
                              hipStream_t stream) {
    (void)n_in; (void)out_size; (void)ws_size;
    const float* predict = (const float*)d_in[0];
    const float* targets = (const float*)d_in[1];
    const int nT = in_sizes[1] / 7;
    float* out = (float*)d_out;
    char* ws = (char*)d_ws;
    double* gsumd = (double*)ws;            // 4*1024*8 = 32768 B
    int* gcnti = (int*)(ws + 32768);        // 2*1024*4 =  8192 B

    heatmap_main<<<NBLK, 512, 0, stream>>>(predict, targets, nT, out,
                                           gsumd, gcnti);
    heatmap_finalize<<<1, 512, 0, stream>>>(gsumd, gcnti, out);
}